// Round 12
// baseline (208.920 us; speedup 1.0000x reference)
//
#include <hip/hip_runtime.h>

// ---------------------------------------------------------------------------
// SparseGRUBrain: N=70000, H=8, E=1.12M, B=8.
// Pipeline (per call):
//   memset(cnt,cursor) -> hist (rank = atomic rank per tgt bucket)
//   -> alloc (block scan + one global atomic per block; + calT transpose)
//   -> edge_prep (scatter 4B edge index into CSR slot; stream calE[i]=calT[src[i]])
//   -> gru_main (one wave per neuron; sparse loop: eIdx -> direct fp32 W reads
//      broadcast across the 8 batch lanes; xor reduce-scatter dense tail).
// No weight records: only 4.5MB of scattered writes (vs 72MB in R11).
// Workspace (bytes):
//   [0,      280K)   cnt
//   [448K,   +4)     cursor
//   [512K,   +560K)  rowCnt (int2 per neuron: {begin, count})
//   [1280K,  +4.5M)  rank
//   [6M,     +2.24M) calT (N x 8 f32)
//   [9M,     +4.5M)  eIdxCSR
//   [14M,    +35.9M) calE (E x 8 f32, edge order)
// ---------------------------------------------------------------------------

__device__ __forceinline__ float fast_sigmoid(float x) {
    return 1.0f / (1.0f + __expf(-x));
}
__device__ __forceinline__ float fast_tanh(float x) {
    return 2.0f / (1.0f + __expf(-2.0f * x)) - 1.0f;
}

// fma 8 fp32 (two float4) into acc[8] with scalar c
#define FMA8F(acc, v0, v1, c)                                                  \
    {                                                                          \
        acc[0] += (v0).x * (c); acc[1] += (v0).y * (c);                        \
        acc[2] += (v0).z * (c); acc[3] += (v0).w * (c);                        \
        acc[4] += (v1).x * (c); acc[5] += (v1).y * (c);                        \
        acc[6] += (v1).z * (c); acc[7] += (v1).w * (c);                        \
    }

// cnt[t]++ per edge; atomic return = this edge's rank within its tgt bucket.
__global__ void hist_kernel(const int* __restrict__ tgt, int* __restrict__ cnt,
                            int* __restrict__ rank, int E) {
    int i = blockIdx.x * blockDim.x + threadIdx.x;
    int base = i * 4;
    if (base + 3 < E) {
        int4 t = *(const int4*)(tgt + base);
        int4 r;
        r.x = atomicAdd(&cnt[t.x], 1);
        r.y = atomicAdd(&cnt[t.y], 1);
        r.z = atomicAdd(&cnt[t.z], 1);
        r.w = atomicAdd(&cnt[t.w], 1);
        *(int4*)(rank + base) = r;
    } else {
        for (int k = base; k < E; ++k) rank[k] = atomicAdd(&cnt[tgt[k]], 1);
    }
}

// Row allocation (block scan + one global atomic per block) fused with the
// calcium transpose. rowCnt = {begin, count}; calT[n][b] = cal[b][n].
__global__ __launch_bounds__(256) void alloc_kernel(const int* __restrict__ cnt,
                                                    int2* __restrict__ rowCnt,
                                                    int* __restrict__ cursor,
                                                    const float* __restrict__ cal,
                                                    float* __restrict__ calT, int N) {
    __shared__ int waveSum[4];
    const int n = blockIdx.x * 256 + threadIdx.x;
    const int lane = threadIdx.x & 63;
    const int wid = threadIdx.x >> 6;
    int c = (n < N) ? cnt[n] : 0;
    int pre = c;
#pragma unroll
    for (int off = 1; off < 64; off <<= 1) {
        int v = __shfl_up(pre, off, 64);
        if (lane >= off) pre += v;
    }
    if (lane == 63) waveSum[wid] = pre;
    __syncthreads();
    if (threadIdx.x == 0) {
        int s0 = waveSum[0], s1 = waveSum[1], s2 = waveSum[2], s3 = waveSum[3];
        int base = atomicAdd(cursor, s0 + s1 + s2 + s3);
        waveSum[0] = base;
        waveSum[1] = base + s0;
        waveSum[2] = base + s0 + s1;
        waveSum[3] = base + s0 + s1 + s2;
    }
    __syncthreads();
    if (n < N) {
        rowCnt[n] = make_int2(waveSum[wid] + (pre - c), c);
        float v[8];
#pragma unroll
        for (int b = 0; b < 8; ++b) v[b] = cal[(size_t)b * N + n];
        float4* o = (float4*)(calT + (size_t)n * 8);
        o[0] = make_float4(v[0], v[1], v[2], v[3]);
        o[1] = make_float4(v[4], v[5], v[6], v[7]);
    }
}

// Per edge: scatter the 4B edge index into its CSR slot (only scattered
// write in the pipeline) and stream calE[i] = calT[src[i]] (32B, edge order).
__global__ __launch_bounds__(256) void edge_prep(
    const int* __restrict__ src, const int* __restrict__ tgt,
    const int* __restrict__ rank, const int2* __restrict__ rowCnt,
    const float* __restrict__ calT, int* __restrict__ eIdxCSR,
    float* __restrict__ calE, int E) {
    int i = blockIdx.x * 256 + threadIdx.x;
    if (i >= E) return;
    int t = tgt[i];
    eIdxCSR[rowCnt[t].x + rank[i]] = i;
    const float4* ca = (const float4*)(calT + (size_t)src[i] * 8);
    float4 c0 = ca[0], c1 = ca[1];
    float4* o = (float4*)(calE + (size_t)i * 8);
    o[0] = c0;
    o[1] = c1;
}

// xor reduce-scatter over the 8 s-lanes: input v[0..7] partials per lane,
// output = fully-reduced value for element index s (lane bits 3,4,5).
__device__ __forceinline__ float rscatter(float v[8], int lane) {
    const bool s0 = (lane & 8) != 0;
    const bool s1 = (lane & 16) != 0;
    const bool s2 = (lane & 32) != 0;
    float w0, w1, w2, w3, x0, x1;
    { float k = s0 ? v[1] : v[0], g = s0 ? v[0] : v[1]; w0 = k + __shfl_xor(g, 8, 64); }
    { float k = s0 ? v[3] : v[2], g = s0 ? v[2] : v[3]; w1 = k + __shfl_xor(g, 8, 64); }
    { float k = s0 ? v[5] : v[4], g = s0 ? v[4] : v[5]; w2 = k + __shfl_xor(g, 8, 64); }
    { float k = s0 ? v[7] : v[6], g = s0 ? v[6] : v[7]; w3 = k + __shfl_xor(g, 8, 64); }
    { float k = s1 ? w1 : w0, g = s1 ? w0 : w1; x0 = k + __shfl_xor(g, 16, 64); }
    { float k = s1 ? w3 : w2, g = s1 ? w2 : w3; x1 = k + __shfl_xor(g, 16, 64); }
    float k = s2 ? x1 : x0, g = s2 ? x0 : x1;
    return k + __shfl_xor(g, 32, 64);
}

// Main: one wave per neuron, 256-thread blocks (4 neurons). lane = s*8 + b.
// Sparse loop: eIdx (sequential 4B) -> 6 broadcast float4 W loads + one
// coalesced calE scalar per lane. All level-2 loads independent.
__global__ __launch_bounds__(256) void gru_main(
    const float* __restrict__ hidden,
    const int* __restrict__ eIdxCSR, const float* __restrict__ calE,
    const float* __restrict__ Wz, const float* __restrict__ Wr,
    const float* __restrict__ Wh,
    const float* __restrict__ Uz, const float* __restrict__ Ur,
    const float* __restrict__ Uh, const float* __restrict__ bz,
    const float* __restrict__ br, const float* __restrict__ bh,
    const float* __restrict__ proj, const int2* __restrict__ rowCnt,
    float* __restrict__ outCal, float* __restrict__ outHid, int N) {
    const int lane = threadIdx.x & 63;
    const int n = blockIdx.x * 4 + (threadIdx.x >> 6);
    if (n >= N) return;
    const int s = lane >> 3;  // slot / h-element index
    const int b = lane & 7;   // batch

    const int2 rc = rowCnt[n];
    const int start = rc.x;
    const int end = rc.x + rc.y;

    // ---- hoisted dense-phase loads (latency hides under the sparse loop) ----
    const float hvS = hidden[((b * N + n) << 3) + s];
    const int ub = (n << 6) + (s << 3);
    float4 uz0 = *(const float4*)(Uz + ub);
    float4 uz1 = *(const float4*)(Uz + ub + 4);
    float4 ur0 = *(const float4*)(Ur + ub);
    float4 ur1 = *(const float4*)(Ur + ub + 4);
    float4 uh0 = *(const float4*)(Uh + ub);
    float4 uh1 = *(const float4*)(Uh + ub + 4);
    const float bzS = bz[(n << 3) + s];
    const float brS = br[(n << 3) + s];
    const float bhS = bh[(n << 3) + s];
    const float pjS = proj[s];

    float az[8] = {0, 0, 0, 0, 0, 0, 0, 0};
    float ar[8] = {0, 0, 0, 0, 0, 0, 0, 0};
    float ah[8] = {0, 0, 0, 0, 0, 0, 0, 0};

    // ---- sparse phase: lane s handles CSR slots j = start+s, +8, ... ----
    for (int j = start + s; j < end; j += 8) {
        int e = eIdxCSR[j];
        size_t eo = (size_t)e << 3;
        const float4* wz4 = (const float4*)(Wz + eo);
        const float4* wr4 = (const float4*)(Wr + eo);
        const float4* wh4 = (const float4*)(Wh + eo);
        float4 z0 = wz4[0], z1 = wz4[1];
        float4 r0 = wr4[0], r1 = wr4[1];
        float4 h0 = wh4[0], h1 = wh4[1];
        float c = calE[eo + b];
        FMA8F(az, z0, z1, c);
        FMA8F(ar, r0, r1, c);
        FMA8F(ah, h0, h1, c);
    }

    // ---- slot-parallel recurrent partials for h = s ----
    az[0] += hvS * uz0.x; az[1] += hvS * uz0.y; az[2] += hvS * uz0.z; az[3] += hvS * uz0.w;
    az[4] += hvS * uz1.x; az[5] += hvS * uz1.y; az[6] += hvS * uz1.z; az[7] += hvS * uz1.w;
    ar[0] += hvS * ur0.x; ar[1] += hvS * ur0.y; ar[2] += hvS * ur0.z; ar[3] += hvS * ur0.w;
    ar[4] += hvS * ur1.x; ar[5] += hvS * ur1.y; ar[6] += hvS * ur1.z; ar[7] += hvS * ur1.w;

    // ---- reduce-scatter -> element-s scalars ----
    float AZ = rscatter(az, lane);
    float AR = rscatter(ar, lane);
    float z = fast_sigmoid(AZ + bzS);
    float r = fast_sigmoid(AR + brS);
    float rhS = r * hvS;

    ah[0] += rhS * uh0.x; ah[1] += rhS * uh0.y; ah[2] += rhS * uh0.z; ah[3] += rhS * uh0.w;
    ah[4] += rhS * uh1.x; ah[5] += rhS * uh1.y; ah[6] += rhS * uh1.z; ah[7] += rhS * uh1.w;
    float AH = rscatter(ah, lane);
    float ht = fast_tanh(AH + bhS);
    float hn = (1.0f - z) * hvS + z * ht;

    // ---- projection: butterfly all-reduce over s ----
    float cv = hn * pjS;
    cv += __shfl_xor(cv, 8, 64);
    cv += __shfl_xor(cv, 16, 64);
    cv += __shfl_xor(cv, 32, 64);

    outHid[((b * N + n) << 3) + s] = hn;
    if (s == 0) outCal[b * N + n] = fmaxf(cv, 0.0f);
}

extern "C" void kernel_launch(void* const* d_in, const int* in_sizes, int n_in,
                              void* d_out, int out_size, void* d_ws, size_t ws_size,
                              hipStream_t stream) {
    const float* calcium = (const float*)d_in[0];
    const float* hidden  = (const float*)d_in[1];
    const int*   src     = (const int*)d_in[2];
    const int*   tgt     = (const int*)d_in[3];
    const float* Wz      = (const float*)d_in[4];
    const float* Wr      = (const float*)d_in[5];
    const float* Wh      = (const float*)d_in[6];
    const float* Uz      = (const float*)d_in[7];
    const float* Ur      = (const float*)d_in[8];
    const float* Uh      = (const float*)d_in[9];
    const float* bz      = (const float*)d_in[10];
    const float* br      = (const float*)d_in[11];
    const float* bh      = (const float*)d_in[12];
    const float* proj    = (const float*)d_in[13];

    const int E = in_sizes[2];
    const int H = in_sizes[13];           // 8
    const int N = in_sizes[10] / H;       // 70000
    (void)n_in; (void)out_size; (void)ws_size;

    float* out = (float*)d_out;
    float* outCal = out;
    float* outHid = out + (size_t)in_sizes[0];

    char* ws = (char*)d_ws;
    int*   cnt     = (int*)ws;
    int*   cursor  = (int*)(ws + (448 << 10));
    int2*  rowCnt  = (int2*)(ws + (512 << 10));
    int*   rank    = (int*)(ws + (1280 << 10));
    float* calT    = (float*)(ws + (6 << 20));
    int*   eIdxCSR = (int*)(ws + (9 << 20));
    float* calE    = (float*)(ws + (14 << 20));

    // zero cnt [0,280K) and cursor (at 448K) in one memset
    hipMemsetAsync(ws, 0, (448 << 10) + 4, stream);

    hist_kernel<<<((E + 3) / 4 + 255) / 256, 256, 0, stream>>>(tgt, cnt, rank, E);
    alloc_kernel<<<(N + 255) / 256, 256, 0, stream>>>(
        cnt, rowCnt, cursor, calcium, calT, N);
    edge_prep<<<(E + 255) / 256, 256, 0, stream>>>(
        src, tgt, rank, rowCnt, calT, eIdxCSR, calE, E);
    gru_main<<<(N + 3) / 4, 256, 0, stream>>>(
        hidden, eIdxCSR, calE, Wz, Wr, Wh, Uz, Ur, Uh, bz, br, bh, proj,
        rowCnt, outCal, outHid, N);
}